// Round 4
// baseline (7019.865 us; speedup 1.0000x reference)
//
#include <hip/hip_runtime.h>
#include <hip/hip_bf16.h>
#include <stdint.h>

// BertBiLstmCrf: B=64 T=512 H=768 LH=384 L=12
// prep -> [gemm_xp(p) -> lstm_rec(p)] x8 -> fc_em -> viterbi
// lstm_rec v2: 24 persistent WGs (12/dir), W_hh slice in REGISTERS,
// h exchange via sc1 atomic loads/stores (no fences -> L2 stays warm),
// flag-array barrier with ballot poll. XP layout [s][n][b].

#define NB 64
#define NT 512
#define NH 768
#define NLH 384
#define NPH 8
#define PS 64
#define NEGV -1000.0f

typedef __attribute__((ext_vector_type(4))) float f32x4;
typedef __attribute__((ext_vector_type(8))) short bf16x8;
typedef unsigned short u16;
typedef unsigned int u32;
typedef unsigned long long u64;

__device__ __forceinline__ u16 f2bf(float f) {
  __hip_bfloat16 h = __float2bfloat16(f);
  return *reinterpret_cast<u16*>(&h);
}
__device__ __forceinline__ float bf2f(u16 u) {
  union { u32 i; float f; } v; v.i = ((u32)u) << 16; return v.f;
}
__device__ __forceinline__ u32 pack2(float a, float b) {
  return (u32)f2bf(a) | ((u32)f2bf(b) << 16);
}
__device__ __forceinline__ float bfx(uint2 v, int r) {
  u32 w = (r & 2) ? v.y : v.x;
  u16 h = (r & 1) ? (u16)(w >> 16) : (u16)(w & 0xffff);
  return bf2f(h);
}
__device__ __forceinline__ float sigm(float x) {
  x = fminf(fmaxf(x, -60.f), 60.f);
  return 1.0f / (1.0f + __expf(-x));
}
__device__ __forceinline__ float tanh_(float x) {
  x = fminf(fmaxf(x, -30.f), 30.f);
  return 2.0f / (1.0f + __expf(-2.0f * x)) - 1.0f;
}

// ---- prep ------------------------------------------------------------------
__global__ __launch_bounds__(256) void prep_kernel(
    const float* bihf, const float* bhhf, const float* bihb, const float* bhhb,
    const float* h0, const float* c0, float* bias2, u16* hraw, float* cbuf,
    u32* flags) {
  int t = blockIdx.x * 256 + threadIdx.x;
  if (t < 1536) bias2[t] = bihf[t] + bhhf[t];
  else if (t < 3072) bias2[t] = bihb[t - 1536] + bhhb[t - 1536];
  if (t < 32) flags[t] = 0;
  if (t < 2 * NB * NLH) {
    hraw[t] = f2bf(h0[t]);   // slots 0,1 = dir 0,1 (parity 0), layout [b][j]
    int dir = t / 24576, r2 = t % 24576;
    int j = r2 / 64, b = r2 % 64;
    cbuf[t] = c0[(size_t)(dir * 64 + b) * 384 + j];  // cbuf[dir][j][b]
  }
}

// ---- gemm_xp: XPc[(s*3072 + n)*64 + b] = X[b, t(s,dir)] @ Wih^T + bias ------
__global__ __launch_bounds__(256) void gemm_xp(
    const float* __restrict__ A, const float* __restrict__ Wf,
    const float* __restrict__ Wb, const float* __restrict__ bias2,
    u16* __restrict__ XPc, int phase) {
  __shared__ __align__(16) u16 As[128][40];
  __shared__ __align__(16) u16 Bs[128][40];
  int nb = blockIdx.x;        // 0..23
  int mb = blockIdx.y;        // 0..31
  int dir = (nb >= 12) ? 1 : 0;
  const float* Bm = dir ? Wb : Wf;
  int n0g = nb * 128;
  int n0 = n0g - dir * 1536;
  int m0 = mb * 128;
  int tf0 = PS * phase, tb0 = (NT - 1) - PS * phase;
  int tid = threadIdx.x;
  int lane = tid & 63, wv = tid >> 6;
  int wm = (wv >> 1) * 64, wn = (wv & 1) * 64;
  int qr = lane & 15, qk8 = (lane >> 4) * 8, qm = (lane >> 4) * 4;

  f32x4 acc[4][4] = {};
  for (int kk = 0; kk < 768; kk += 32) {
    __syncthreads();
#pragma unroll
    for (int u = 0; u < 4; ++u) {
      int c = tid + u * 256;
      int row = c >> 3, q4 = (c & 7) * 4;
      int m = m0 + row;
      int sloc = m >> 6, b = m & 63;
      int t = dir ? (tb0 - sloc) : (tf0 + sloc);
      float4 av = *(const float4*)&A[(size_t)(b * NT + t) * 768 + kk + q4];
      float4 bv = *(const float4*)&Bm[(size_t)(n0 + row) * 768 + kk + q4];
      uint2 ap; ap.x = pack2(av.x, av.y); ap.y = pack2(av.z, av.w);
      uint2 bp; bp.x = pack2(bv.x, bv.y); bp.y = pack2(bv.z, bv.w);
      *(uint2*)&As[row][q4] = ap;
      *(uint2*)&Bs[row][q4] = bp;
    }
    __syncthreads();
    bf16x8 af[4], bfr[4];
#pragma unroll
    for (int i = 0; i < 4; ++i) af[i] = *(const bf16x8*)&As[wm + i * 16 + qr][qk8];
#pragma unroll
    for (int j = 0; j < 4; ++j) bfr[j] = *(const bf16x8*)&Bs[wn + j * 16 + qr][qk8];
#pragma unroll
    for (int i = 0; i < 4; ++i)
#pragma unroll
      for (int j = 0; j < 4; ++j)
        acc[i][j] = __builtin_amdgcn_mfma_f32_16x16x32_bf16(af[i], bfr[j], acc[i][j], 0, 0, 0);
  }
#pragma unroll
  for (int j = 0; j < 4; ++j) {
    int n = n0g + wn + j * 16 + qr;
    float bv = bias2[n];
#pragma unroll
    for (int i = 0; i < 4; ++i) {
      int mrel = wm + i * 16 + qm;           // 0..124 (r adds 0..3)
      int b0 = mrel & 63;
      int sl = mb * 2 + (mrel >> 6);
      uint2 pk;
      pk.x = pack2(acc[i][j][0] + bv, acc[i][j][1] + bv);
      pk.y = pack2(acc[i][j][2] + bv, acc[i][j][3] + bv);
      *(uint2*)&XPc[((size_t)sl * 3072 + n) * 64 + b0] = pk;
    }
  }
}

// ---- lstm_rec v2 ------------------------------------------------------------
// 24 WGs: dir = wg/12, gidx = wg%12, owns j in [gidx*32, gidx*32+32) x 4 gates.
// Wave wv: mgrp = wv>>1 (batches mgrp*32..+32), jt = wv&1 (j half).
__global__ __launch_bounds__(256, 1) void lstm_rec(
    const float* __restrict__ Whhf, const float* __restrict__ Whhb,
    const u16* __restrict__ XPc, u16* hraw, float* cbuf,
    u16* __restrict__ LOUT, u32* flags, int phase) {
  __shared__ __align__(16) u16 hsm[64][392];   // h_{t-1} staged [b][k]
  __shared__ __align__(16) u16 hxch[64][32];   // h_t repack scratch [b][jloc]
  int wg = blockIdx.x;
  int dir = wg / 12, gidx = wg % 12;
  int j0 = gidx * 32;
  int tid = threadIdx.x;
  int lane = tid & 63, wv = tid >> 6;
  int mgrp = wv >> 1, jt = wv & 1;
  int wm3 = mgrp * 32;
  int ll = lane & 15, qk8 = (lane >> 4) * 8, qm = (lane >> 4) * 4;
  int jloc = jt * 16 + ll, jg = j0 + jloc;
  const float* Whh = dir ? Whhb : Whhf;

  // W_hh fragments in registers: Bf[kk][g] covers rows g*384 + jg, k = kk*32+qk8
  bf16x8 Bf[12][4];
#pragma unroll
  for (int kk = 0; kk < 12; ++kk)
#pragma unroll
    for (int g = 0; g < 4; ++g) {
      const float* wp = &Whh[(size_t)(g * 384 + jg) * 384 + kk * 32 + qk8];
      float4 w0 = *(const float4*)wp;
      float4 w1 = *(const float4*)(wp + 4);
      union { u32 u[4]; bf16x8 v; } cv;
      cv.u[0] = pack2(w0.x, w0.y); cv.u[1] = pack2(w0.z, w0.w);
      cv.u[2] = pack2(w1.x, w1.y); cv.u[3] = pack2(w1.z, w1.w);
      Bf[kk][g] = cv.v;
    }

  float cst[2][4];
#pragma unroll
  for (int mt = 0; mt < 2; ++mt)
    *(f32x4*)cst[mt] = *(const f32x4*)&cbuf[((size_t)dir * 384 + jg) * 64 + wm3 + mt * 16 + qm];

  int tf0 = PS * phase, tb0 = (NT - 1) - PS * phase;
  const size_t hslot = (size_t)NB * NLH;
  u32* myflag = &flags[dir * 16 + gidx];

  for (int s = 0; s < PS; ++s) {
    int stepidx = phase * PS + s;
    int t = dir ? (tb0 - s) : (tf0 + s);
    int pp = s & 1;
    const u64* hsrc = (const u64*)(hraw + (size_t)(pp * 2 + dir) * hslot);
    u64* hdst = (u64*)(hraw + (size_t)((pp ^ 1) * 2 + dir) * hslot);

    // XP prefetch (plain cached loads, layout [s][n][b])
    uint2 xpv[2][4];
    const u16* xpb = &XPc[(((size_t)s * 3072) + dir * 1536 + jg) * 64];
#pragma unroll
    for (int mt = 0; mt < 2; ++mt)
#pragma unroll
      for (int g = 0; g < 4; ++g)
        xpv[mt][g] = *(const uint2*)&xpb[(size_t)g * 384 * 64 + wm3 + mt * 16 + qm];

    // stage h_{t-1}: 6144 x 8B coherent loads -> LDS (row = 96 u64)
#pragma unroll
    for (int i = 0; i < 24; ++i) {
      int u = tid + i * 256;
      int b = u / 96, c8 = u - b * 96;
      u64 v = __hip_atomic_load(hsrc + (size_t)b * 96 + c8,
                                __ATOMIC_RELAXED, __HIP_MEMORY_SCOPE_AGENT);
      *(u64*)&hsm[b][c8 * 4] = v;
    }
    __syncthreads();

    // gates = h @ W^T (A from LDS, B from registers)
    f32x4 acc[2][4] = {};
#pragma unroll
    for (int kk = 0; kk < 12; ++kk) {
      bf16x8 af0 = *(const bf16x8*)&hsm[wm3 + ll][kk * 32 + qk8];
      bf16x8 af1 = *(const bf16x8*)&hsm[wm3 + 16 + ll][kk * 32 + qk8];
#pragma unroll
      for (int g = 0; g < 4; ++g) {
        acc[0][g] = __builtin_amdgcn_mfma_f32_16x16x32_bf16(af0, Bf[kk][g], acc[0][g], 0, 0, 0);
        acc[1][g] = __builtin_amdgcn_mfma_f32_16x16x32_bf16(af1, Bf[kk][g], acc[1][g], 0, 0, 0);
      }
    }

    // combine i,f,g,o -> c,h  (lane owns j=jg, batches wm3+mt*16+qm+r)
#pragma unroll
    for (int mt = 0; mt < 2; ++mt)
#pragma unroll
      for (int r = 0; r < 4; ++r) {
        int b = wm3 + mt * 16 + qm + r;
        float pi = acc[mt][0][r] + bfx(xpv[mt][0], r);
        float pf = acc[mt][1][r] + bfx(xpv[mt][1], r);
        float pg = acc[mt][2][r] + bfx(xpv[mt][2], r);
        float po = acc[mt][3][r] + bfx(xpv[mt][3], r);
        float ig = sigm(pi), fg = sigm(pf), gg = tanh_(pg), og = sigm(po);
        float cv = fg * cst[mt][r] + ig * gg;
        cst[mt][r] = cv;
        u16 hb = f2bf(og * tanh_(cv));
        hxch[b][jloc] = hb;
        LOUT[((size_t)b * NT + t) * 768 + dir * 384 + jg] = hb;
      }
    __syncthreads();

    // repack [b][4j] -> publish via coherent 8B stores
#pragma unroll
    for (int i = 0; i < 2; ++i) {
      int u = tid + i * 256;
      int b = u >> 3, q8 = u & 7;
      u64 v = *(const u64*)&hxch[b][q8 * 4];
      __hip_atomic_store(hdst + (size_t)b * 96 + gidx * 8 + q8, v,
                         __ATOMIC_RELAXED, __HIP_MEMORY_SCOPE_AGENT);
    }
    __syncthreads();  // drains all waves' stores (vmcnt 0 before s_barrier)

    if (tid == 0)
      __hip_atomic_store(myflag, (u32)(stepidx + 1),
                         __ATOMIC_RELEASE, __HIP_MEMORY_SCOPE_AGENT);
    if (wv == 0) {
      int spins = 0;
      while (true) {
        u32 v = (lane < 12)
                    ? __hip_atomic_load(&flags[dir * 16 + lane],
                                        __ATOMIC_RELAXED, __HIP_MEMORY_SCOPE_AGENT)
                    : 0xffffffffu;
        if (~__ballot(v > (u32)stepidx) == 0ull) break;
        __builtin_amdgcn_s_sleep(1);
        if (++spins > (1 << 20)) break;  // liveness guard
      }
    }
    __syncthreads();
  }

  // persist c state
#pragma unroll
  for (int mt = 0; mt < 2; ++mt)
    *(f32x4*)&cbuf[((size_t)dir * 384 + jg) * 64 + wm3 + mt * 16 + qm] = *(f32x4*)cst[mt];
}

// ---- fc_em: emissions = LOUT @ fc_w^T + fc_b --------------------------------
__global__ __launch_bounds__(256) void fc_em(
    const u16* __restrict__ LOUT, const float* __restrict__ fcw,
    const float* __restrict__ fcb, float* __restrict__ em) {
  __shared__ float wsm[12][768];
  __shared__ float wbv[12];
  int tid = threadIdx.x;
  for (int i = tid; i < 12 * 768; i += 256) wsm[i / 768][i % 768] = fcw[i];
  if (tid < 12) wbv[tid] = fcb[tid];
  __syncthreads();
  int lane = tid & 63, wv = tid >> 6;
  for (int r = blockIdx.x * 4 + wv; r < NB * NT; r += gridDim.x * 4) {
    float x[12];
#pragma unroll
    for (int c = 0; c < 12; ++c) x[c] = bf2f(LOUT[(size_t)r * 768 + c * 64 + lane]);
    float sums[12];
#pragma unroll
    for (int l = 0; l < 12; ++l) {
      float pv = 0.f;
#pragma unroll
      for (int c = 0; c < 12; ++c) pv += x[c] * wsm[l][c * 64 + lane];
#pragma unroll
      for (int off = 32; off > 0; off >>= 1) pv += __shfl_xor(pv, off);
      sums[l] = pv + wbv[l];
    }
    if (lane == 0) {
#pragma unroll
      for (int l = 0; l < 12; ++l) em[(size_t)r * 12 + l] = sums[l];
    }
  }
}

// ---- viterbi: one wave per batch --------------------------------------------
__global__ __launch_bounds__(256) void viterbi_k(
    const float* __restrict__ em, const float* __restrict__ trans,
    const int* __restrict__ startp, unsigned char* __restrict__ ptrs,
    float* __restrict__ outp) {
  int tid = threadIdx.x;
  int lane = tid & 63, wv = tid >> 6;
  int b = blockIdx.x * 4 + wv;
  int l = lane;
  int start = startp[0];
  float tr[12];
#pragma unroll
  for (int p = 0; p < 12; ++p) tr[p] = (l < 12) ? trans[l * 12 + p] : NEGV;
  float fv = (l == start) ? 0.f : NEGV;
  for (int t = 1; t < NT; ++t) {
    float feat = (l < 12) ? em[((size_t)b * NT + t) * 12 + l] : 0.f;
    float best = -3.4e38f; int bp = 0;
#pragma unroll
    for (int p = 0; p < 12; ++p) {
      float v = __shfl(fv, p) + tr[p];
      if (v > best) { best = v; bp = p; }
    }
    if (l < 12) {
      fv = best + feat;
      ptrs[((size_t)b * (NT - 1) + (t - 1)) * 12 + l] = (unsigned char)bp;
    }
  }
  float bv = fv; int bi = l;
#pragma unroll
  for (int off = 32; off > 0; off >>= 1) {
    float v2 = __shfl_xor(bv, off); int i2 = __shfl_xor(bi, off);
    if (v2 > bv || (v2 == bv && i2 < bi)) { bv = v2; bi = i2; }
  }
  int nxt = bi;
  if (lane == 0) {
    outp[b] = bv;
    outp[64 + (size_t)b * NT + (NT - 1)] = (float)nxt;
  }
  int pb = (l < 12) ? (int)ptrs[((size_t)b * (NT - 1) + (NT - 2)) * 12 + l] : 0;
  for (int t = NT - 2; t >= 0; --t) {
    int pbn = (t > 0) ? ((l < 12) ? (int)ptrs[((size_t)b * (NT - 1) + (t - 1)) * 12 + l] : 0) : 0;
    nxt = __shfl(pb, nxt);
    if (lane == 0) outp[64 + (size_t)b * NT + t] = (float)nxt;
    pb = pbn;
  }
}

// ---- launch -----------------------------------------------------------------
extern "C" void kernel_launch(void* const* d_in, const int* in_sizes, int n_in,
                              void* d_out, int out_size, void* d_ws, size_t ws_size,
                              hipStream_t stream) {
  const float* X     = (const float*)d_in[0];
  const float* h0    = (const float*)d_in[1];
  const float* c0    = (const float*)d_in[2];
  const float* wihf  = (const float*)d_in[3];
  const float* whhf  = (const float*)d_in[4];
  const float* bihf  = (const float*)d_in[5];
  const float* bhhf  = (const float*)d_in[6];
  const float* wihb  = (const float*)d_in[7];
  const float* whhb  = (const float*)d_in[8];
  const float* bihb  = (const float*)d_in[9];
  const float* bhhb  = (const float*)d_in[10];
  const float* fcw   = (const float*)d_in[11];
  const float* fcb   = (const float*)d_in[12];
  const float* trans = (const float*)d_in[13];
  const int* startp  = (const int*)d_in[14];
  float* outp = (float*)d_out;
  char* ws = (char*)d_ws;

  // workspace layout (total ~74.3 MB)
  float* bias2 = (float*)(ws + 0);                       //     12,288
  u16* hraw    = (u16*)(ws + 12288);                     //    196,608 (4 slots)
  float* cbuf  = (float*)(ws + 208896);                  //    196,608
  u32* flags   = (u32*)(ws + 405504);                    //        128
  u16* XPc     = (u16*)(ws + 409600);                    // 25,165,824
  u16* LOUT    = (u16*)(ws + 25575424);                  // 50,331,648
  float* em    = (float*)(ws + 75907072);                //  1,572,864
  unsigned char* ptrs = (unsigned char*)(ws + 77479936); //    392,448

  prep_kernel<<<192, 256, 0, stream>>>(bihf, bhhf, bihb, bhhb, h0, c0,
                                       bias2, hraw, cbuf, flags);
  for (int p = 0; p < NPH; ++p) {
    gemm_xp<<<dim3(24, 32), 256, 0, stream>>>(X, wihf, wihb, bias2, XPc, p);
    lstm_rec<<<24, 256, 0, stream>>>(whhf, whhb, XPc, hraw, cbuf, LOUT, flags, p);
  }
  fc_em<<<128, 256, 0, stream>>>(LOUT, fcw, fcb, em);
  viterbi_k<<<16, 256, 0, stream>>>(em, trans, startp, ptrs, outp);
}

// Round 6
// 3662.642 us; speedup vs baseline: 1.9166x; 1.9166x over previous
//
#include <hip/hip_runtime.h>
#include <hip/hip_bf16.h>
#include <stdint.h>

// BertBiLstmCrf: B=64 T=512 H=768 LH=384 L=12
// prep -> [gemm_xp(p) -> lstm_rec(p)] x8 -> fc_em -> viterbi
// lstm_rec v4: XCD-0-local persistent recurrence, deadlock-free claim.
// 512 blocks launched; xcd = s_getreg(HW_REG_XCC_ID); non-XCD0 blocks exit.
// XCD0 blocks take rank = fetch_add(claim[phase]); ranks 0..23 are workers
// (12 per direction). h-exchange + flag barrier go through XCD0's L2:
// plain write-through stores + nontemporal (no-L1-allocate) loads, so no
// L1 can ever hold a stale h/flag line. No device-scope ops in the hot loop.

#define NB 64
#define NT 512
#define NH 768
#define NLH 384
#define NPH 8
#define PS 64
#define NEGV -1000.0f

typedef __attribute__((ext_vector_type(4))) float f32x4;
typedef __attribute__((ext_vector_type(8))) short bf16x8;
typedef __attribute__((ext_vector_type(4))) unsigned int u32x4;
typedef unsigned short u16;
typedef unsigned int u32;

__device__ __forceinline__ u16 f2bf(float f) {
  __hip_bfloat16 h = __float2bfloat16(f);
  return *reinterpret_cast<u16*>(&h);
}
__device__ __forceinline__ float bf2f(u16 u) {
  union { u32 i; float f; } v; v.i = ((u32)u) << 16; return v.f;
}
__device__ __forceinline__ u32 pack2(float a, float b) {
  return (u32)f2bf(a) | ((u32)f2bf(b) << 16);
}
__device__ __forceinline__ float bfx(uint2 v, int r) {
  u32 w = (r & 2) ? v.y : v.x;
  u16 h = (r & 1) ? (u16)(w >> 16) : (u16)(w & 0xffff);
  return bf2f(h);
}
__device__ __forceinline__ float sigm(float x) {
  x = fminf(fmaxf(x, -60.f), 60.f);
  return 1.0f / (1.0f + __expf(-x));
}
__device__ __forceinline__ float tanh_(float x) {
  x = fminf(fmaxf(x, -30.f), 30.f);
  return 2.0f / (1.0f + __expf(-2.0f * x)) - 1.0f;
}
__device__ __forceinline__ int xcc_id() {
  u32 v;
  asm volatile("s_getreg_b32 %0, hwreg(HW_REG_XCC_ID)" : "=s"(v));
  return (int)v;
}

// ---- prep ------------------------------------------------------------------
__global__ __launch_bounds__(256) void prep_kernel(
    const float* bihf, const float* bhhf, const float* bihb, const float* bhhb,
    const float* h0, const float* c0, float* bias2, u16* hraw, float* cbuf,
    u32* flags, u32* claim) {
  int t = blockIdx.x * 256 + threadIdx.x;
  if (t < 1536) bias2[t] = bihf[t] + bhhf[t];
  else if (t < 3072) bias2[t] = bihb[t - 1536] + bhhb[t - 1536];
  if (t < 32) flags[t] = 0;
  if (t < 16) claim[t] = 0;
  if (t < 2 * NB * NLH) {
    hraw[t] = f2bf(h0[t]);   // slots 0,1 = dir 0,1 (parity 0), layout [b][j]
    int dir = t / 24576, r2 = t % 24576;
    int j = r2 / 64, b = r2 % 64;
    cbuf[t] = c0[(size_t)(dir * 64 + b) * 384 + j];  // cbuf[dir][j][b]
  }
}

// ---- gemm_xp: XPc[(s*3072 + n)*64 + b] = X[b, t(s,dir)] @ Wih^T + bias ------
__global__ __launch_bounds__(256) void gemm_xp(
    const float* __restrict__ A, const float* __restrict__ Wf,
    const float* __restrict__ Wb, const float* __restrict__ bias2,
    u16* __restrict__ XPc, int phase) {
  __shared__ __align__(16) u16 As[128][40];
  __shared__ __align__(16) u16 Bs[128][40];
  int nb = blockIdx.x;        // 0..23
  int mb = blockIdx.y;        // 0..31
  int dir = (nb >= 12) ? 1 : 0;
  const float* Bm = dir ? Wb : Wf;
  int n0g = nb * 128;
  int n0 = n0g - dir * 1536;
  int m0 = mb * 128;
  int tf0 = PS * phase, tb0 = (NT - 1) - PS * phase;
  int tid = threadIdx.x;
  int lane = tid & 63, wv = tid >> 6;
  int wm = (wv >> 1) * 64, wn = (wv & 1) * 64;
  int qr = lane & 15, qk8 = (lane >> 4) * 8, qm = (lane >> 4) * 4;

  f32x4 acc[4][4] = {};
  for (int kk = 0; kk < 768; kk += 32) {
    __syncthreads();
#pragma unroll
    for (int u = 0; u < 4; ++u) {
      int c = tid + u * 256;
      int row = c >> 3, q4 = (c & 7) * 4;
      int m = m0 + row;
      int sloc = m >> 6, b = m & 63;
      int t = dir ? (tb0 - sloc) : (tf0 + sloc);
      float4 av = *(const float4*)&A[(size_t)(b * NT + t) * 768 + kk + q4];
      float4 bv = *(const float4*)&Bm[(size_t)(n0 + row) * 768 + kk + q4];
      uint2 ap; ap.x = pack2(av.x, av.y); ap.y = pack2(av.z, av.w);
      uint2 bp; bp.x = pack2(bv.x, bv.y); bp.y = pack2(bv.z, bv.w);
      *(uint2*)&As[row][q4] = ap;
      *(uint2*)&Bs[row][q4] = bp;
    }
    __syncthreads();
    bf16x8 af[4], bfr[4];
#pragma unroll
    for (int i = 0; i < 4; ++i) af[i] = *(const bf16x8*)&As[wm + i * 16 + qr][qk8];
#pragma unroll
    for (int j = 0; j < 4; ++j) bfr[j] = *(const bf16x8*)&Bs[wn + j * 16 + qr][qk8];
#pragma unroll
    for (int i = 0; i < 4; ++i)
#pragma unroll
      for (int j = 0; j < 4; ++j)
        acc[i][j] = __builtin_amdgcn_mfma_f32_16x16x32_bf16(af[i], bfr[j], acc[i][j], 0, 0, 0);
  }
#pragma unroll
  for (int j = 0; j < 4; ++j) {
    int n = n0g + wn + j * 16 + qr;
    float bv = bias2[n];
#pragma unroll
    for (int i = 0; i < 4; ++i) {
      int mrel = wm + i * 16 + qm;           // 0..124 (r adds 0..3)
      int b0 = mrel & 63;
      int sl = mb * 2 + (mrel >> 6);
      uint2 pk;
      pk.x = pack2(acc[i][j][0] + bv, acc[i][j][1] + bv);
      pk.y = pack2(acc[i][j][2] + bv, acc[i][j][3] + bv);
      *(uint2*)&XPc[((size_t)sl * 3072 + n) * 64 + b0] = pk;
    }
  }
}

// ---- lstm_rec v4: XCD0-local, deadlock-free --------------------------------
__global__ __launch_bounds__(256, 1) void lstm_rec(
    const float* __restrict__ Whhf, const float* __restrict__ Whhb,
    const u16* __restrict__ XPc, u16* hraw, float* cbuf,
    u16* __restrict__ LOUT, u32* flags, u32* claim, int phase) {
  __shared__ __align__(16) u16 hsm[64][392];   // h_{t-1} staged [b][k]
  __shared__ __align__(16) u16 hxch[64][32];   // h_t repack scratch [b][jloc]
  __shared__ int s_role;
  int tid = threadIdx.x;

  if (tid == 0) {
    int role = -1;
    if (xcc_id() == 0) {
      u32 r = __hip_atomic_fetch_add(&claim[phase], 1u,
                                     __ATOMIC_RELAXED, __HIP_MEMORY_SCOPE_AGENT);
      if (r < 24u) role = (int)r;
    }
    s_role = role;
  }
  __syncthreads();
  int role = s_role;
  if (role < 0) return;                         // not a worker

  int dir = role / 12, gidx = role % 12;
  int j0 = gidx * 32;
  int lane = tid & 63, wv = tid >> 6;
  int mgrp = wv >> 1, jt = wv & 1;
  int wm3 = mgrp * 32;
  int ll = lane & 15, qk8 = (lane >> 4) * 8, qm = (lane >> 4) * 4;
  int jloc = jt * 16 + ll, jg = j0 + jloc;
  const float* Whh = dir ? Whhb : Whhf;

  // W_hh fragments in registers: Bf[kk][g] covers rows g*384 + jg
  bf16x8 Bf[12][4];
#pragma unroll
  for (int kk = 0; kk < 12; ++kk)
#pragma unroll
    for (int g = 0; g < 4; ++g) {
      const float* wp = &Whh[(size_t)(g * 384 + jg) * 384 + kk * 32 + qk8];
      float4 w0 = *(const float4*)wp;
      float4 w1 = *(const float4*)(wp + 4);
      union { u32 u[4]; bf16x8 v; } cv;
      cv.u[0] = pack2(w0.x, w0.y); cv.u[1] = pack2(w0.z, w0.w);
      cv.u[2] = pack2(w1.x, w1.y); cv.u[3] = pack2(w1.z, w1.w);
      Bf[kk][g] = cv.v;
    }

  float cst[2][4];
#pragma unroll
  for (int mt = 0; mt < 2; ++mt)
    *(f32x4*)cst[mt] = *(const f32x4*)&cbuf[((size_t)dir * 384 + jg) * 64 + wm3 + mt * 16 + qm];

  int tf0 = PS * phase, tb0 = (NT - 1) - PS * phase;
  const size_t hslot = (size_t)NB * NLH;
  u32* myflag = &flags[dir * 16 + gidx];

  for (int s = 0; s < PS; ++s) {
    int stepidx = phase * PS + s;
    int t = dir ? (tb0 - s) : (tf0 + s);
    int pp = s & 1;
    const u16* hsrc = hraw + (size_t)(pp * 2 + dir) * hslot;
    u16* hdst = hraw + (size_t)((pp ^ 1) * 2 + dir) * hslot;

    // XP prefetch (plain loads, layout [s][n][b]) — overlaps h staging
    uint2 xpv[2][4];
    const u16* xpb = &XPc[(((size_t)s * 3072) + dir * 1536 + jg) * 64];
#pragma unroll
    for (int mt = 0; mt < 2; ++mt)
#pragma unroll
      for (int g = 0; g < 4; ++g)
        xpv[mt][g] = *(const uint2*)&xpb[(size_t)g * 384 * 64 + wm3 + mt * 16 + qm];

    // stage h_{t-1}: 3072 x 16B NONTEMPORAL loads (L1-bypass -> XCD0 L2)
#pragma unroll
    for (int i = 0; i < 12; ++i) {
      int u = tid + i * 256;
      int b = u / 48, c16 = u % 48;
      u32x4 v = __builtin_nontemporal_load(
          (const u32x4*)&hsrc[(size_t)b * 384 + c16 * 8]);
      *(u32x4*)&hsm[b][c16 * 8] = v;
    }
    __syncthreads();

    // gates = h @ W^T (A from LDS, B from registers)
    f32x4 acc[2][4] = {};
#pragma unroll
    for (int kk = 0; kk < 12; ++kk) {
      bf16x8 af0 = *(const bf16x8*)&hsm[wm3 + ll][kk * 32 + qk8];
      bf16x8 af1 = *(const bf16x8*)&hsm[wm3 + 16 + ll][kk * 32 + qk8];
#pragma unroll
      for (int g = 0; g < 4; ++g) {
        acc[0][g] = __builtin_amdgcn_mfma_f32_16x16x32_bf16(af0, Bf[kk][g], acc[0][g], 0, 0, 0);
        acc[1][g] = __builtin_amdgcn_mfma_f32_16x16x32_bf16(af1, Bf[kk][g], acc[1][g], 0, 0, 0);
      }
    }

    // combine i,f,g,o -> c,h  (lane owns j=jg, batches wm3+mt*16+qm+r)
#pragma unroll
    for (int mt = 0; mt < 2; ++mt)
#pragma unroll
      for (int r = 0; r < 4; ++r) {
        int b = wm3 + mt * 16 + qm + r;
        float pi = acc[mt][0][r] + bfx(xpv[mt][0], r);
        float pf = acc[mt][1][r] + bfx(xpv[mt][1], r);
        float pg = acc[mt][2][r] + bfx(xpv[mt][2], r);
        float po = acc[mt][3][r] + bfx(xpv[mt][3], r);
        float ig = sigm(pi), fg = sigm(pf), gg = tanh_(pg), og = sigm(po);
        float cv = fg * cst[mt][r] + ig * gg;
        cst[mt][r] = cv;
        u16 hb = f2bf(og * tanh_(cv));
        hxch[b][jloc] = hb;
        LOUT[((size_t)b * NT + t) * 768 + dir * 384 + jg] = hb;
      }
    __syncthreads();

    // publish h_t slice: 256 x 16B plain write-through stores -> XCD0 L2
    {
      int b = tid >> 2, c = tid & 3;
      *(u32x4*)&hdst[(size_t)b * 384 + j0 + c * 8] = *(const u32x4*)&hxch[b][c * 8];
    }
    __syncthreads();  // vmcnt(0) drain: all h stores in L2 before flag store

    if (tid == 0)
      __hip_atomic_store(myflag, (u32)(stepidx + 1),
                         __ATOMIC_RELAXED, __HIP_MEMORY_SCOPE_WORKGROUP);
    if (wv == 0) {
      int spins = 0;
      while (true) {
        u32 v = 0xffffffffu;
        if (lane < 12)
          v = __builtin_nontemporal_load(&flags[dir * 16 + lane]);
        asm volatile("" ::: "memory");  // no CSE across poll iterations
        if (~__ballot(v > (u32)stepidx) == 0ull) break;
        __builtin_amdgcn_s_sleep(1);
        if (++spins > (1 << 14)) break;  // fail-fast liveness guard
      }
    }
    __syncthreads();
  }

  // persist c state
#pragma unroll
  for (int mt = 0; mt < 2; ++mt)
    *(f32x4*)&cbuf[((size_t)dir * 384 + jg) * 64 + wm3 + mt * 16 + qm] = *(f32x4*)cst[mt];
}

// ---- fc_em: emissions = LOUT @ fc_w^T + fc_b --------------------------------
__global__ __launch_bounds__(256) void fc_em(
    const u16* __restrict__ LOUT, const float* __restrict__ fcw,
    const float* __restrict__ fcb, float* __restrict__ em) {
  __shared__ float wsm[12][768];
  __shared__ float wbv[12];
  int tid = threadIdx.x;
  for (int i = tid; i < 12 * 768; i += 256) wsm[i / 768][i % 768] = fcw[i];
  if (tid < 12) wbv[tid] = fcb[tid];
  __syncthreads();
  int lane = tid & 63, wv = tid >> 6;
  for (int r = blockIdx.x * 4 + wv; r < NB * NT; r += gridDim.x * 4) {
    float x[12];
#pragma unroll
    for (int c = 0; c < 12; ++c) x[c] = bf2f(LOUT[(size_t)r * 768 + c * 64 + lane]);
    float sums[12];
#pragma unroll
    for (int l = 0; l < 12; ++l) {
      float pv = 0.f;
#pragma unroll
      for (int c = 0; c < 12; ++c) pv += x[c] * wsm[l][c * 64 + lane];
#pragma unroll
      for (int off = 32; off > 0; off >>= 1) pv += __shfl_xor(pv, off);
      sums[l] = pv + wbv[l];
    }
    if (lane == 0) {
#pragma unroll
      for (int l = 0; l < 12; ++l) em[(size_t)r * 12 + l] = sums[l];
    }
  }
}

// ---- viterbi: one wave per batch --------------------------------------------
__global__ __launch_bounds__(256) void viterbi_k(
    const float* __restrict__ em, const float* __restrict__ trans,
    const int* __restrict__ startp, unsigned char* __restrict__ ptrs,
    float* __restrict__ outp) {
  int tid = threadIdx.x;
  int lane = tid & 63, wv = tid >> 6;
  int b = blockIdx.x * 4 + wv;
  int l = lane;
  int start = startp[0];
  float tr[12];
#pragma unroll
  for (int p = 0; p < 12; ++p) tr[p] = (l < 12) ? trans[l * 12 + p] : NEGV;
  float fv = (l == start) ? 0.f : NEGV;
  for (int t = 1; t < NT; ++t) {
    float feat = (l < 12) ? em[((size_t)b * NT + t) * 12 + l] : 0.f;
    float best = -3.4e38f; int bp = 0;
#pragma unroll
    for (int p = 0; p < 12; ++p) {
      float v = __shfl(fv, p) + tr[p];
      if (v > best) { best = v; bp = p; }
    }
    if (l < 12) {
      fv = best + feat;
      ptrs[((size_t)b * (NT - 1) + (t - 1)) * 12 + l] = (unsigned char)bp;
    }
  }
  float bv = fv; int bi = l;
#pragma unroll
  for (int off = 32; off > 0; off >>= 1) {
    float v2 = __shfl_xor(bv, off); int i2 = __shfl_xor(bi, off);
    if (v2 > bv || (v2 == bv && i2 < bi)) { bv = v2; bi = i2; }
  }
  int nxt = bi;
  if (lane == 0) {
    outp[b] = bv;
    outp[64 + (size_t)b * NT + (NT - 1)] = (float)nxt;
  }
  int pb = (l < 12) ? (int)ptrs[((size_t)b * (NT - 1) + (NT - 2)) * 12 + l] : 0;
  for (int t = NT - 2; t >= 0; --t) {
    int pbn = (t > 0) ? ((l < 12) ? (int)ptrs[((size_t)b * (NT - 1) + (t - 1)) * 12 + l] : 0) : 0;
    nxt = __shfl(pb, nxt);
    if (lane == 0) outp[64 + (size_t)b * NT + t] = (float)nxt;
    pb = pbn;
  }
}

// ---- launch -----------------------------------------------------------------
extern "C" void kernel_launch(void* const* d_in, const int* in_sizes, int n_in,
                              void* d_out, int out_size, void* d_ws, size_t ws_size,
                              hipStream_t stream) {
  const float* X     = (const float*)d_in[0];
  const float* h0    = (const float*)d_in[1];
  const float* c0    = (const float*)d_in[2];
  const float* wihf  = (const float*)d_in[3];
  const float* whhf  = (const float*)d_in[4];
  const float* bihf  = (const float*)d_in[5];
  const float* bhhf  = (const float*)d_in[6];
  const float* wihb  = (const float*)d_in[7];
  const float* whhb  = (const float*)d_in[8];
  const float* bihb  = (const float*)d_in[9];
  const float* bhhb  = (const float*)d_in[10];
  const float* fcw   = (const float*)d_in[11];
  const float* fcb   = (const float*)d_in[12];
  const float* trans = (const float*)d_in[13];
  const int* startp  = (const int*)d_in[14];
  float* outp = (float*)d_out;
  char* ws = (char*)d_ws;

  // workspace layout (total ~77.9 MB)
  float* bias2 = (float*)(ws + 0);                       //     12,288
  u16* hraw    = (u16*)(ws + 12288);                     //    196,608 (4 slots)
  float* cbuf  = (float*)(ws + 208896);                  //    196,608
  u32* flags   = (u32*)(ws + 405504);                    //        128
  u32* claim   = (u32*)(ws + 405632);                    //         64
  u16* XPc     = (u16*)(ws + 409600);                    // 25,165,824
  u16* LOUT    = (u16*)(ws + 25575424);                  // 50,331,648
  float* em    = (float*)(ws + 75907072);                //  1,572,864
  unsigned char* ptrs = (unsigned char*)(ws + 77479936); //    392,448

  prep_kernel<<<192, 256, 0, stream>>>(bihf, bhhf, bihb, bhhb, h0, c0,
                                       bias2, hraw, cbuf, flags, claim);
  for (int p = 0; p < NPH; ++p) {
    gemm_xp<<<dim3(24, 32), 256, 0, stream>>>(X, wihf, wihb, bias2, XPc, p);
    lstm_rec<<<512, 256, 0, stream>>>(whhf, whhb, XPc, hraw, cbuf, LOUT,
                                      flags, claim, p);
  }
  fc_em<<<128, 256, 0, stream>>>(LOUT, fcw, fcb, em);
  viterbi_k<<<16, 256, 0, stream>>>(em, trans, startp, ptrs, outp);
}